// Round 2
// baseline (287.686 us; speedup 1.0000x reference)
//
#include <hip/hip_runtime.h>
#include <hip/hip_bf16.h>

typedef __bf16 bf16x4 __attribute__((ext_vector_type(4)));
typedef __bf16 bf16x8 __attribute__((ext_vector_type(8)));
typedef float  f32x4  __attribute__((ext_vector_type(4)));
typedef float  f32x16 __attribute__((ext_vector_type(16)));

#define MFMA32(a,b,c) __builtin_amdgcn_mfma_f32_32x32x16_bf16((a),(b),(c),0,0,0)

// lgkm-only workgroup barrier: LDS producer/consumer ordering preserved,
// y-stores and x-prefetch loads stay in flight across it (no vmcnt drain).
#define BAR_LDS() asm volatile("s_waitcnt lgkmcnt(0)\n\ts_barrier" ::: "memory")

// Merged-weight TT forward, software-pipelined.
//   W01[m0][(m1*8+r2)][(n0*8+n1)] = sum_r1 c0[m0][r1*4+n0] * c1[(r1*8+m1)][(r2*8+n1)]
//   W23[(m2*8+m3)][(n2*32+n3*8+r2)] = sum_r3 c2[(r2*8+m2)][(r3*8+n2)] * c3[(r3*8+m3)][n3]
// Steps s = it*2+q (16 total). Phase s executes {stage B of s-1  ||  stage A of s}
// with ONE lgkm barrier per phase; hb is double-buffered (A writes hb[s&1],
// B reads hb[(s-1)&1]) so the two stages never touch the same buffer.
// W23 lives in per-wave REGISTER B-frags (w23f, 64 VGPR) -> stage B's LDS read
// traffic is halved vs R1 and only hb is read in steady state.
// 32x32x16 layouts (HW-validated): A[m=lane&31][k=(lane>>5)*8+j] == B[k][n=lane&31],
// D[row=(reg&3)+8*(reg>>2)+4*(lane>>5)][col=lane&31].

__global__ __launch_bounds__(256, 2) void tt_kernel(
    const float* __restrict__ x,  const float* __restrict__ c0,
    const float* __restrict__ c1, const float* __restrict__ c2,
    const float* __restrict__ c3, const float* __restrict__ bias,
    float* __restrict__ y)
{
    __shared__ __align__(16) __bf16 hb[2][16384];  // 64 KB double-buffered H
    __shared__ __align__(16) __bf16 xt[2][2048];   //  8 KB double-buffered X

    const int tid  = threadIdx.x;
    const int wid  = tid >> 6;
    const int lane = tid & 63;
    const int hh   = lane >> 5;   // MFMA k-half
    const int c32  = lane & 31;   // MFMA row/col id
    const int rt   = wid & 1;     // row-tile role
    const int ct   = wid >> 1;    // batch role b^

    // ---- x staging geometry (per thread) ----
    const int bsel = tid >> 7, xcol = tid & 31, k0q = (tid >> 5) & 3;
    const int xtoff = (bsel * 32 + xcol) * 32 + ((k0q ^ (xcol & 3)) << 3);

#define LOAD_X(itn) do { \
    const float* xp_ = x + (size_t)((blockIdx.x * 8 + (itn)) * 2 + bsel) * 1024 + xcol; \
    _Pragma("unroll") \
    for (int j = 0; j < 8; ++j) xv[j] = xp_[(k0q * 8 + j) * 32]; \
  } while (0)

#define WRITE_XT(itb) do { \
    bf16x8 v_; \
    _Pragma("unroll") \
    for (int j = 0; j < 8; ++j) v_[j] = (__bf16)xv[j]; \
    *(bf16x8*)&xt[itb][xtoff] = v_; \
  } while (0)

#define READ_XF(itb) do { \
    _Pragma("unroll") \
    for (int kt = 0; kt < 2; ++kt) \
      xf[kt] = *(const bf16x8*) \
        &xt[itb][(ct * 32 + c32) * 32 + (((kt * 2 + hh) ^ (c32 & 3)) << 3)]; \
  } while (0)

#define STAGE_A(qc, buf) do { \
    _Pragma("unroll") \
    for (int m0h = 0; m0h < 4; ++m0h) { \
      f32x16 acc_ = {}; \
      acc_ = MFMA32(w01f[(qc) * 4 + m0h][0], xf[0], acc_); \
      acc_ = MFMA32(w01f[(qc) * 4 + m0h][1], xf[1], acc_); \
      _Pragma("unroll") \
      for (int p = 0; p < 4; ++p) { \
        bf16x4 o_; \
        _Pragma("unroll") \
        for (int i = 0; i < 4; ++i) o_[i] = (__bf16)acc_[p * 4 + i]; \
        const int cl_ = ct * 32 + m0h * 8 + rt * 4 + p; \
        *(bf16x4*)&hb[buf][cl_ * 256 + ((c32 ^ (cl_ & 31)) << 3) + hh * 4] = o_; \
      } \
    } \
  } while (0)

#define STAGE_B_EPI(qc, buf, itp) do { \
    const __bf16* brow_ = &hb[buf][(ct * 32 + c32) * 256]; \
    f32x16 a2a_ = {}, a2b_ = {}; \
    _Pragma("unroll") \
    for (int kt = 0; kt < 16; kt += 2) { \
      const int op0_ = ((kt * 2 + hh) ^ c32) << 3; \
      const int op1_ = ((kt * 2 + 2 + hh) ^ c32) << 3; \
      a2a_ = MFMA32(*(const bf16x8*)&brow_[op0_], w23f[kt], a2a_); \
      a2b_ = MFMA32(*(const bf16x8*)&brow_[op1_], w23f[kt + 1], a2b_); \
    } \
    const size_t yb_ = (size_t)((blockIdx.x * 8 + (itp)) * 2 + ct) * 4096 \
                       + (qc) * 2048 + rt * 32 + c32; \
    _Pragma("unroll") \
    for (int p = 0; p < 4; ++p) \
      _Pragma("unroll") \
      for (int i = 0; i < 4; ++i) \
        y[yb_ + p * 512 + (hh * 4 + i) * 64] = \
            (a2a_[p * 4 + i] + a2b_[p * 4 + i]) + bv[qc][p][i]; \
  } while (0)

    float xv[8];
    LOAD_X(0);   // issue it=0 x loads first (longest latency)

    // ---- one-time: W23 -> hb[1] (temp, A-frag swizzled: oct = (k>>3)^(row&31)) ----
    {
      const int r = tid >> 2, kb = (tid & 3) * 64;
      const int m2 = r >> 3, m3 = r & 7;
      float c3v[8][4];
      #pragma unroll
      for (int r3 = 0; r3 < 8; ++r3)
        #pragma unroll
        for (int n3 = 0; n3 < 4; ++n3)
          c3v[r3][n3] = c3[(r3 * 8 + m3) * 4 + n3];
      for (int j = 0; j < 64; ++j) {
        const int k = kb + j;
        const int n2 = k >> 5, n3 = (k >> 3) & 3, r2 = k & 7;
        float s = 0.f;
        #pragma unroll
        for (int r3 = 0; r3 < 8; ++r3)
          s += c2[(r2 * 8 + m2) * 64 + r3 * 8 + n2] * c3v[r3][n3];
        hb[1][r * 256 + (((k >> 3) ^ (r & 31)) << 3) + (k & 7)] = (__bf16)s;
      }
    }

    // ---- one-time: W01 A-frags in registers (wave holds its rt slice) ----
    bf16x8 w01f[8][2];
    {
      const int row = rt * 32 + c32, m1 = row >> 3, r2w = row & 7;
      float c1row[8][8];
      #pragma unroll
      for (int r1 = 0; r1 < 8; ++r1)
        #pragma unroll
        for (int n1 = 0; n1 < 8; ++n1)
          c1row[r1][n1] = c1[(r1 * 8 + m1) * 64 + r2w * 8 + n1];
      for (int m0 = 0; m0 < 8; ++m0) {
        #pragma unroll
        for (int kt = 0; kt < 2; ++kt) {
          const int n0 = kt * 2 + hh;
          #pragma unroll
          for (int j = 0; j < 8; ++j) {
            float s = 0.f;
            #pragma unroll
            for (int r1 = 0; r1 < 8; ++r1)
              s += c0[m0 * 32 + r1 * 4 + n0] * c1row[r1][j];
            w01f[m0][kt][j] = (__bf16)s;
          }
        }
      }
    }

    // ---- one-time: bias regs; feature = q*2048 + p*512 + (hh*4+i)*64 + rt*32 + c32
    float bv[2][4][4];
    #pragma unroll
    for (int q = 0; q < 2; ++q)
      #pragma unroll
      for (int p = 0; p < 4; ++p)
        #pragma unroll
        for (int i = 0; i < 4; ++i)
          bv[q][p][i] = bias[q * 2048 + p * 512 + (hh * 4 + i) * 64 + rt * 32 + c32];

    WRITE_XT(0);   // xv(it=0) has arrived by now
    BAR_LDS();     // publishes W23-temp (hb[1]) and xt[0]

    // ================= phase 0: read w23f; stage A(step 0) -> hb[0] =================
    bf16x8 w23f[16];
    {
      const __bf16* wrow = &hb[1][(rt * 32 + c32) * 256];
      #pragma unroll
      for (int kt = 0; kt < 16; ++kt)
        w23f[kt] = *(const bf16x8*)&wrow[((kt * 2 + hh) ^ c32) << 3];
    }
    bf16x8 xf[2];
    READ_XF(0);
    LOAD_X(1);
    STAGE_A(0, 0);
    BAR_LDS();

    // ================= steady phases =================
    #pragma unroll 1
    for (int it = 0; it < 7; ++it) {
      // phase 2it+1: A(it,q1)->hb[1] || B(it,q0)<-hb[0] + epi; stage xt for it+1
      STAGE_A(1, 1);
      STAGE_B_EPI(0, 0, it);
      WRITE_XT((it + 1) & 1);
      BAR_LDS();
      // phase 2it+2: xf<-xt; x loads for it+2; A(it+1,q0)->hb[0] || B(it,q1)<-hb[1]+epi
      READ_XF((it + 1) & 1);
      if (it < 6) LOAD_X(it + 2);
      STAGE_A(0, 0);
      STAGE_B_EPI(1, 1, it);
      BAR_LDS();
    }
    // ================= tail (it = 7) =================
    STAGE_A(1, 1);
    STAGE_B_EPI(0, 0, 7);
    BAR_LDS();
    STAGE_B_EPI(1, 1, 7);

#undef LOAD_X
#undef WRITE_XT
#undef READ_XF
#undef STAGE_A
#undef STAGE_B_EPI
}

extern "C" void kernel_launch(void* const* d_in, const int* in_sizes, int n_in,
                              void* d_out, int out_size, void* d_ws, size_t ws_size,
                              hipStream_t stream) {
    const float* x    = (const float*)d_in[0];
    const float* c0   = (const float*)d_in[1];
    const float* c1   = (const float*)d_in[2];
    const float* c2   = (const float*)d_in[3];
    const float* c3   = (const float*)d_in[4];
    const float* bias = (const float*)d_in[5];
    float* yout = (float*)d_out;
    // persistent: 512 blocks (2/CU, 72 KB LDS), 8 iters x 2 batches each
    tt_kernel<<<512, 256, 0, stream>>>(x, c0, c1, c2, c3, bias, yout);
}

// Round 3
// 191.329 us; speedup vs baseline: 1.5036x; 1.5036x over previous
//
#include <hip/hip_runtime.h>
#include <hip/hip_bf16.h>

typedef __bf16 bf16x4 __attribute__((ext_vector_type(4)));
typedef __bf16 bf16x8 __attribute__((ext_vector_type(8)));
typedef float  f32x4  __attribute__((ext_vector_type(4)));
typedef float  f32x16 __attribute__((ext_vector_type(16)));

#define MFMA32(a,b,c) __builtin_amdgcn_mfma_f32_32x32x16_bf16((a),(b),(c),0,0,0)

// lgkm-only workgroup barrier: LDS producer/consumer ordering preserved,
// y-stores and global loads stay in flight across it (no vmcnt drain).
#define BAR_LDS() asm volatile("s_waitcnt lgkmcnt(0)\n\ts_barrier" ::: "memory")

// Merged-weight TT forward, occupancy-first restructure (R3).
//   W01[m0][(m1*8+r2)][(n0*8+n1)] = sum_r1 c0[m0][r1*4+n0] * c1[(r1*8+m1)*64+(r2*8+n1)]
//   W23[(m2*8+m3)][(n2*32+n3*8+r2)] = sum_r3 c2[(r2*8+m2)*64+(r3*8+n2)] * c3[(r3*8+m3)*4+n3]
// prep_kernel materializes both tables into d_ws in FRAG-LINEAR layouts:
//   ws01[(((rt*8+m0)*2+kt)*2+hh)*32 + c32][8]  (A-frag for stage A)
//   ws23[((rt*16+kt)*2+hh)*32 + c32][8]        (B-frag for stage B, operand-swapped)
// Main kernel (4096 blocks x 2 batches, NO intra-block pipeline):
//   stage A: H = W01^(m0 quad) @ Xt -> hb (LDS, swizzled)   [w01 frags: 8 global L1 loads]
//   stage B: Y[cols][m2m3] = hb @ W23^T, K=256 -> y + bias  [w23 frags: 16 global L1 loads]
// LDS = 36 KB (hb 32 + xt 4) -> 3-4 blocks/CU; latency hidden by cross-block
// phase staggering instead of per-block double-buffering (R2's spill lesson).
// 32x32x16 layouts (HW-validated): A[m=lane&31][k=(lane>>5)*8+j] == B[k][n=lane&31],
// D[row=(reg&3)+8*(reg>>2)+4*(lane>>5)][col=lane&31].

__global__ __launch_bounds__(256) void prep_kernel(
    const float* __restrict__ c0, const float* __restrict__ c1,
    const float* __restrict__ c2, const float* __restrict__ c3,
    __bf16* __restrict__ ws)
{
    const int gid = blockIdx.x * 256 + threadIdx.x;   // 32768 threads
    if (gid < 16384) {
      // W01 frag table
      const int j   = gid & 7,        c32 = (gid >> 3) & 31;
      const int hh  = (gid >> 8) & 1, kt  = (gid >> 9) & 1;
      const int m0  = (gid >> 10) & 7, rt = (gid >> 13) & 1;
      const int row = rt * 32 + c32, m1 = row >> 3, r2 = row & 7;
      const int n0  = kt * 2 + hh, n1 = j;
      float s = 0.f;
      #pragma unroll
      for (int r1 = 0; r1 < 8; ++r1)
        s += c0[m0 * 32 + r1 * 4 + n0] * c1[(r1 * 8 + m1) * 64 + r2 * 8 + n1];
      ws[gid] = (__bf16)s;
    } else {
      // W23 frag table
      const int idx = gid - 16384;
      const int j   = idx & 7,        c32 = (idx >> 3) & 31;
      const int hh  = (idx >> 8) & 1, kt  = (idx >> 9) & 15;
      const int rt  = (idx >> 13) & 1;
      const int row = rt * 32 + c32, m2 = row >> 3, m3 = row & 7;
      const int k   = (kt * 2 + hh) * 8 + j;
      const int n2  = k >> 5, n3 = (k >> 3) & 3, r2 = k & 7;
      float s = 0.f;
      #pragma unroll
      for (int r3 = 0; r3 < 8; ++r3)
        s += c2[(r2 * 8 + m2) * 64 + r3 * 8 + n2] * c3[(r3 * 8 + m3) * 4 + n3];
      ws[gid] = (__bf16)s;
    }
}

__global__ __launch_bounds__(256, 3) void tt_kernel(
    const float* __restrict__ x, const float* __restrict__ bias,
    const __bf16* __restrict__ ws, float* __restrict__ y)
{
    __shared__ __align__(16) __bf16 hb[16384];  // 32 KB
    __shared__ __align__(16) __bf16 xt[2048];   //  4 KB

    const int tid  = threadIdx.x;
    const int wid  = tid >> 6;
    const int lane = tid & 63;
    const int hh   = lane >> 5;   // MFMA k-half
    const int c32  = lane & 31;   // MFMA row/col id
    const int rt   = wid & 1;     // row-tile role
    const int ct   = wid >> 1;    // batch role b^

    const __bf16* ws01 = ws;
    const __bf16* ws23 = ws + 16384;
    const int b0 = blockIdx.x * 2;

#define LOAD_W01(qc, DST) do { \
    _Pragma("unroll") \
    for (int m0h = 0; m0h < 4; ++m0h) \
      _Pragma("unroll") \
      for (int kt = 0; kt < 2; ++kt) \
        DST[m0h][kt] = *(const bf16x8*)&ws01[rt * 8192 + ((qc) * 4 + m0h) * 1024 \
                                             + kt * 512 + hh * 256 + c32 * 8]; \
  } while (0)

#define STAGE_A(WQ) do { \
    _Pragma("unroll") \
    for (int m0h = 0; m0h < 4; ++m0h) { \
      f32x16 acc_ = {}; \
      acc_ = MFMA32(WQ[m0h][0], xf[0], acc_); \
      acc_ = MFMA32(WQ[m0h][1], xf[1], acc_); \
      _Pragma("unroll") \
      for (int p = 0; p < 4; ++p) { \
        bf16x4 o_; \
        _Pragma("unroll") \
        for (int i = 0; i < 4; ++i) o_[i] = (__bf16)acc_[p * 4 + i]; \
        const int cl_ = ct * 32 + m0h * 8 + rt * 4 + p; \
        *(bf16x4*)&hb[cl_ * 256 + ((c32 ^ (cl_ & 31)) << 3) + hh * 4] = o_; \
      } \
    } \
  } while (0)

#define STAGE_B_EPI(qc) do { \
    const __bf16* brow_ = &hb[(ct * 32 + c32) * 256]; \
    const __bf16* wrow_ = ws23 + rt * 8192 + hh * 256 + c32 * 8; \
    f32x16 a2a_ = {}, a2b_ = {}; \
    _Pragma("unroll") \
    for (int kt = 0; kt < 16; kt += 2) { \
      const bf16x8 w0_ = *(const bf16x8*)&wrow_[kt * 512]; \
      const bf16x8 w1_ = *(const bf16x8*)&wrow_[(kt + 1) * 512]; \
      const bf16x8 b0_ = *(const bf16x8*)&brow_[((kt * 2 + hh) ^ c32) << 3]; \
      const bf16x8 b1_ = *(const bf16x8*)&brow_[((kt * 2 + 2 + hh) ^ c32) << 3]; \
      a2a_ = MFMA32(b0_, w0_, a2a_); \
      a2b_ = MFMA32(b1_, w1_, a2b_); \
    } \
    const size_t yb_ = (size_t)(b0 + ct) * 4096 + (qc) * 2048 + rt * 32 + c32; \
    const int bb_ = (qc) * 2048 + rt * 32 + c32; \
    _Pragma("unroll") \
    for (int p = 0; p < 4; ++p) \
      _Pragma("unroll") \
      for (int i = 0; i < 4; ++i) \
        y[yb_ + p * 512 + (hh * 4 + i) * 64] = \
            (a2a_[p * 4 + i] + a2b_[p * 4 + i]) + bias[bb_ + p * 512 + (hh * 4 + i) * 64]; \
  } while (0)

    // ---- setup: issue x loads + q0 W01 frag loads, stage xt ----
    const int bsel = tid >> 7, xcol = tid & 31, k0q = (tid >> 5) & 3;
    float xv[8];
    {
      const float* xp = x + (size_t)(b0 + bsel) * 1024 + xcol;
      #pragma unroll
      for (int j = 0; j < 8; ++j) xv[j] = xp[(k0q * 8 + j) * 32];
    }
    bf16x8 w01q[4][2];
    LOAD_W01(0, w01q);
    {
      bf16x8 v;
      #pragma unroll
      for (int j = 0; j < 8; ++j) v[j] = (__bf16)xv[j];
      *(bf16x8*)&xt[(bsel * 32 + xcol) * 32 + ((k0q ^ (xcol & 3)) << 3)] = v;
    }
    BAR_LDS();

    // ---- q0 ----
    bf16x8 xf[2];
    #pragma unroll
    for (int kt = 0; kt < 2; ++kt)
      xf[kt] = *(const bf16x8*)
        &xt[(ct * 32 + c32) * 32 + (((kt * 2 + hh) ^ (c32 & 3)) << 3)];
    STAGE_A(w01q);
    bf16x8 w01n[4][2];
    LOAD_W01(1, w01n);          // issue q1 frags; latency hides under stage B q0
    BAR_LDS();
    STAGE_B_EPI(0);
    BAR_LDS();                  // WAR: q1's stage A rewrites hb

    // ---- q1 ----
    STAGE_A(w01n);
    BAR_LDS();
    STAGE_B_EPI(1);

#undef LOAD_W01
#undef STAGE_A
#undef STAGE_B_EPI
}

extern "C" void kernel_launch(void* const* d_in, const int* in_sizes, int n_in,
                              void* d_out, int out_size, void* d_ws, size_t ws_size,
                              hipStream_t stream) {
    const float* x    = (const float*)d_in[0];
    const float* c0   = (const float*)d_in[1];
    const float* c1   = (const float*)d_in[2];
    const float* c2   = (const float*)d_in[3];
    const float* c3   = (const float*)d_in[4];
    const float* bias = (const float*)d_in[5];
    float* yout = (float*)d_out;
    __bf16* ws = (__bf16*)d_ws;   // 64 KB: W01 + W23 frag tables

    prep_kernel<<<128, 256, 0, stream>>>(c0, c1, c2, c3, ws);
    // 4096 blocks x 2 batches each; 36 KB LDS -> 3-4 blocks/CU
    tt_kernel<<<4096, 256, 0, stream>>>(x, bias, ws, yout);
}